// Round 1
// baseline (2295.460 us; speedup 1.0000x reference)
//
#include <hip/hip_runtime.h>
#include <math.h>

// Problem constants (SpiralDeblock)
#define B      16
#define N_IN   7000
#define N_OUT  28000
#define C      64          // C_IN == C_OUT == 64
#define S      9
#define NNZ    (3 * N_OUT) // 84000
#define F      (S * C)     // 576

// ---------------------------------------------------------------------------
// Kernel 1: scatter-add pooling
//   pooled[b, row[i], c] += x[b, col[i], c] * values[i]
// Block: 256 threads = 4 nnz entries x 64 channels. Grid: (NNZ/4, B).
// ---------------------------------------------------------------------------
__global__ void spiral_scatter(const float* __restrict__ x,
                               const float* __restrict__ values,
                               const int*   __restrict__ row,
                               const int*   __restrict__ col,
                               float*       __restrict__ pooled) {
    const int c  = threadIdx.x & 63;
    const int li = threadIdx.x >> 6;          // 0..3
    const int i  = blockIdx.x * 4 + li;       // nnz index (NNZ % 4 == 0)
    const int b  = blockIdx.y;

    const int   r  = row[i];
    const int   cl = col[i];
    const float v  = values[i];

    const float xv = x[((size_t)b * N_IN + cl) * C + c];
    atomicAdd(&pooled[((size_t)b * N_OUT + r) * C + c], xv * v);
}

// ---------------------------------------------------------------------------
// Kernel 2: gather 9 spiral neighbors -> feat(576), GEMM with weight(576x64),
// bias add, ELU. One 64-thread block per (n, b); thread o computes out[b,n,o].
// feat staged in LDS (broadcast reads); weight reads are wave-coalesced
// (64 consecutive floats per iteration) and L2-resident (147 KB total).
// ---------------------------------------------------------------------------
__global__ void spiral_gemm(const float* __restrict__ pooled,
                            const int*   __restrict__ sp,
                            const float* __restrict__ weight,
                            const float* __restrict__ bias,
                            float*       __restrict__ out) {
    __shared__ float feat[F];
    __shared__ int   sidx[S];

    const int n = blockIdx.x;
    const int b = blockIdx.y;
    const int o = threadIdx.x;   // 0..63

    if (o < S) sidx[o] = sp[n * S + o];
    __syncthreads();

    #pragma unroll
    for (int s = 0; s < S; ++s) {
        feat[s * C + o] = pooled[((size_t)b * N_OUT + sidx[s]) * C + o];
    }
    __syncthreads();

    float acc = bias[o];
    #pragma unroll 8
    for (int f = 0; f < F; ++f) {
        acc = fmaf(feat[f], weight[f * C + o], acc);
    }

    // ELU (alpha = 1): x > 0 ? x : exp(x) - 1
    const float r = acc > 0.0f ? acc : expm1f(acc);
    out[((size_t)b * N_OUT + n) * C + o] = r;
}

// ---------------------------------------------------------------------------
// Launch
// Inputs (setup_inputs order):
//   0: x               (B, N_IN, C)   float32
//   1: values          (NNZ,)         float32
//   2: weight          (F, C)         float32
//   3: bias            (C,)           float32
//   4: row             (NNZ,)         int32
//   5: col             (NNZ,)         int32
//   6: spiral_indices  (N_OUT, S)     int32
// Output: (B, N_OUT, C) float32
// Workspace: pooled (B, N_OUT, C) float32 = 114,688,000 bytes
// ---------------------------------------------------------------------------
extern "C" void kernel_launch(void* const* d_in, const int* in_sizes, int n_in,
                              void* d_out, int out_size, void* d_ws, size_t ws_size,
                              hipStream_t stream) {
    const float* x      = (const float*)d_in[0];
    const float* values = (const float*)d_in[1];
    const float* weight = (const float*)d_in[2];
    const float* bias   = (const float*)d_in[3];
    const int*   row    = (const int*)d_in[4];
    const int*   col    = (const int*)d_in[5];
    const int*   sp     = (const int*)d_in[6];
    float*       out    = (float*)d_out;

    float* pooled = (float*)d_ws;
    const size_t pooled_bytes = (size_t)B * N_OUT * C * sizeof(float);

    // d_ws is re-poisoned to 0xAA before every launch — zero it ourselves.
    hipMemsetAsync(pooled, 0, pooled_bytes, stream);

    // Scatter-add pooling.
    dim3 sgrid(NNZ / 4, B);
    spiral_scatter<<<sgrid, 256, 0, stream>>>(x, values, row, col, pooled);

    // Gather + GEMM + ELU.
    dim3 ggrid(N_OUT, B);
    spiral_gemm<<<ggrid, 64, 0, stream>>>(pooled, sp, weight, bias, out);
}

// Round 3
// 373.558 us; speedup vs baseline: 6.1449x; 6.1449x over previous
//
#include <hip/hip_runtime.h>
#include <math.h>

// Problem constants (SpiralDeblock)
#define B      16
#define N_IN   7000
#define N_OUT  28000
#define C      64          // C_IN == C_OUT == 64
#define S      9
#define NNZ    (3 * N_OUT) // 84000
#define F      (S * C)     // 576
#define KB     (F / 32)    // 18 k-blocks of 32 for mfma 16x16x32

typedef short bf16x8 __attribute__((ext_vector_type(8)));  // 8 bf16 = 4 VGPRs
typedef float f32x4  __attribute__((ext_vector_type(4)));

// fp32 -> bf16 round-to-nearest-even (bit pattern as ushort)
static __device__ __forceinline__ unsigned short f2bf(float f) {
    unsigned u = __float_as_uint(f);
    u += 0x7fffu + ((u >> 16) & 1u);
    return (unsigned short)(u >> 16);
}

// ---------------------------------------------------------------------------
// CSR build: histogram -> exclusive scan -> placement.
// ---------------------------------------------------------------------------
__global__ void hist_kernel(const int* __restrict__ row, int* __restrict__ cnt) {
    int i = blockIdx.x * 256 + threadIdx.x;
    if (i < NNZ) atomicAdd(&cnt[row[i]], 1);
}

__global__ void scan_kernel(const int* __restrict__ cnt,
                            int* __restrict__ offs, int* __restrict__ cursor) {
    __shared__ int tmp[1024];
    int carry = 0;
    for (int base = 0; base < N_OUT; base += 1024) {
        int i = base + (int)threadIdx.x;
        int v = (i < N_OUT) ? cnt[i] : 0;
        tmp[threadIdx.x] = v;
        __syncthreads();
        #pragma unroll
        for (int off = 1; off < 1024; off <<= 1) {
            int t = (threadIdx.x >= (unsigned)off) ? tmp[threadIdx.x - off] : 0;
            __syncthreads();
            tmp[threadIdx.x] += t;
            __syncthreads();
        }
        int excl = tmp[threadIdx.x] - v;
        if (i < N_OUT) { offs[i] = carry + excl; cursor[i] = carry + excl; }
        carry += tmp[1023];
        __syncthreads();
    }
    if (threadIdx.x == 0) offs[N_OUT] = carry;
}

__global__ void place_kernel(const int* __restrict__ row, const int* __restrict__ col,
                             const float* __restrict__ values,
                             int* __restrict__ cursor,
                             int* __restrict__ ecol, float* __restrict__ eval) {
    int i = blockIdx.x * 256 + threadIdx.x;
    if (i < NNZ) {
        int pos = atomicAdd(&cursor[row[i]], 1);
        ecol[pos] = col[i];
        eval[pos] = values[i];
    }
}

// ---------------------------------------------------------------------------
// Pooling: pooled_bf16[b, r, c] = sum_e x[b, ecol[e], c] * eval[e]  (e in row r)
// Block 256 = 4 waves; each wave owns one output row, loops all 16 batches.
// ---------------------------------------------------------------------------
__global__ void pool_kernel(const float* __restrict__ x,
                            const int*   __restrict__ ecol,
                            const float* __restrict__ eval,
                            const int*   __restrict__ offs,
                            unsigned short* __restrict__ pooled) {
    const int lane = threadIdx.x & 63;
    const int wave = threadIdx.x >> 6;
    const int r = blockIdx.x * 4 + wave;   // 7000 blocks * 4 == 28000

    const int start = offs[r], end = offs[r + 1];

    float acc[B];
    #pragma unroll
    for (int b = 0; b < B; ++b) acc[b] = 0.f;

    for (int e = start; e < end; ++e) {
        const int   cl = ecol[e];
        const float v  = eval[e];
        const float* xp = x + (size_t)cl * C + lane;
        #pragma unroll
        for (int b = 0; b < B; ++b)
            acc[b] = fmaf(xp[(size_t)b * N_IN * C], v, acc[b]);
    }
    #pragma unroll
    for (int b = 0; b < B; ++b)
        pooled[((size_t)b * N_OUT + r) * C + lane] = f2bf(acc[b]);
}

// ---------------------------------------------------------------------------
// Pack weight (576x64 fp32, row-major [f][o]) into MFMA B-fragment lane order:
// packedW[((kb*4 + nt)*64 + lane)*8 + j] = bf16( W[(kb*32 + quad*8 + j)*64 + nt*16 + lm] )
// so the GEMM's B-frag load is one coalesced 16 B load per lane.
// ---------------------------------------------------------------------------
__global__ void packw_kernel(const float* __restrict__ w, unsigned short* __restrict__ pw) {
    const int kb   = blockIdx.x;        // 0..17
    const int nt   = threadIdx.x >> 6;  // 0..3
    const int lane = threadIdx.x & 63;
    const int lm   = lane & 15;
    const int quad = lane >> 4;

    unsigned short v[8];
    #pragma unroll
    for (int j = 0; j < 8; ++j) {
        const int k = kb * 32 + quad * 8 + j;
        const int n = nt * 16 + lm;
        v[j] = f2bf(w[(size_t)k * C + n]);
    }
    unsigned short* dst = pw + ((size_t)(kb * 4 + nt) * 64 + lane) * 8;
    #pragma unroll
    for (int j = 0; j < 8; ++j) dst[j] = v[j];
}

// ---------------------------------------------------------------------------
// Gathered GEMM via MFMA 16x16x32 bf16.
// Block 256 = 4 waves, each wave computes 64 rows x 64 cols: acc[t][nt], t,nt in 0..3.
// A-frag: lane holds A[m = lane&15][k = quad*8 + j] -> 8 contiguous bf16 channels of
//         pooled row sp[m, s] -> one 16 B global load, no LDS needed.
// B-frag: coalesced 16 B load from packedW (L2-resident, 72 KB).
// C/D:    col = lane&15, row = quad*4 + reg.
// ---------------------------------------------------------------------------
__global__ __launch_bounds__(256, 2)
void spiral_mfma(const unsigned short* __restrict__ pooled,
                 const bf16x8*         __restrict__ packedW,
                 const int*            __restrict__ sp,
                 const float*          __restrict__ bias,
                 float*                __restrict__ out) {
    const int b    = blockIdx.y;
    const int wave = threadIdx.x >> 6;
    const int lane = threadIdx.x & 63;
    const int lm   = lane & 15;
    const int quad = lane >> 4;
    const int m_base = blockIdx.x * 256 + wave * 64;

    // Lane i pre-loads sp[m_base+i, 0..8]; distributed to tiles via shfl.
    int spv[S];
    {
        int r = m_base + lane;
        if (r >= N_OUT) r = N_OUT - 1;
        #pragma unroll
        for (int s = 0; s < S; ++s) spv[s] = sp[r * S + s];
    }

    const unsigned short* poolb = pooled + (size_t)b * N_OUT * C;

    f32x4 acc[4][4];
    #pragma unroll
    for (int t = 0; t < 4; ++t)
        #pragma unroll
        for (int nt = 0; nt < 4; ++nt)
            acc[t][nt] = (f32x4){0.f, 0.f, 0.f, 0.f};

    #pragma unroll
    for (int s = 0; s < S; ++s) {
        int rowi[4];
        #pragma unroll
        for (int t = 0; t < 4; ++t)
            rowi[t] = __shfl(spv[s], t * 16 + lm, 64);

        #pragma unroll
        for (int half = 0; half < 2; ++half) {
            const int kb = s * 2 + half;
            const int c0 = half * 32 + quad * 8;

            bf16x8 a[4];
            #pragma unroll
            for (int t = 0; t < 4; ++t)
                a[t] = *(const bf16x8*)(poolb + (size_t)rowi[t] * C + c0);

            #pragma unroll
            for (int nt = 0; nt < 4; ++nt) {
                const bf16x8 bf = packedW[(kb * 4 + nt) * 64 + lane];
                #pragma unroll
                for (int t = 0; t < 4; ++t)
                    acc[t][nt] = __builtin_amdgcn_mfma_f32_16x16x32_bf16(
                        a[t], bf, acc[t][nt], 0, 0, 0);
            }
        }
    }

    // Epilogue: bias + ELU + store.
    #pragma unroll
    for (int nt = 0; nt < 4; ++nt) {
        const int n = nt * 16 + lm;
        const float bs = bias[n];
        #pragma unroll
        for (int t = 0; t < 4; ++t) {
            #pragma unroll
            for (int reg = 0; reg < 4; ++reg) {
                const int r = m_base + t * 16 + quad * 4 + reg;
                if (r < N_OUT) {
                    float v = acc[t][nt][reg] + bs;
                    v = v > 0.f ? v : expm1f(v);
                    out[((size_t)b * N_OUT + r) * C + n] = v;
                }
            }
        }
    }
}

// ---------------------------------------------------------------------------
// Launch.
// Inputs: 0:x 1:values 2:weight 3:bias 4:row 5:col 6:spiral_indices
// Workspace layout (bytes, all 128-aligned):
//   pooled_bf16 : 0            .. 57,344,000
//   packedW     : 57,344,000   .. +73,728
//   offs        : +((N_OUT+1)*4 -> padded)
//   cursor, cnt : N_OUT*4 each
//   ecol, eval  : NNZ*4 each
// Total ~58.4 MB  (R0 proved ws >= 114.7 MB)
// ---------------------------------------------------------------------------
extern "C" void kernel_launch(void* const* d_in, const int* in_sizes, int n_in,
                              void* d_out, int out_size, void* d_ws, size_t ws_size,
                              hipStream_t stream) {
    const float* x      = (const float*)d_in[0];
    const float* values = (const float*)d_in[1];
    const float* weight = (const float*)d_in[2];
    const float* bias   = (const float*)d_in[3];
    const int*   row    = (const int*)d_in[4];
    const int*   col    = (const int*)d_in[5];
    const int*   sp     = (const int*)d_in[6];
    float*       out    = (float*)d_out;

    char* ws = (char*)d_ws;
    size_t off = 0;
    unsigned short* pooled  = (unsigned short*)(ws + off); off += (size_t)B * N_OUT * C * 2;      // 57,344,000
    unsigned short* packedW = (unsigned short*)(ws + off); off += (size_t)KB * 4 * 64 * 8 * 2;    // 73,728
    int*   offs   = (int*)(ws + off); off += ((size_t)(N_OUT + 1) * 4 + 124) / 128 * 128;
    int*   cursor = (int*)(ws + off); off += (size_t)N_OUT * 4 + 128;
    int*   cnt    = (int*)(ws + off); off += (size_t)N_OUT * 4 + 128;
    int*   ecol   = (int*)(ws + off); off += (size_t)NNZ * 4;
    float* eval   = (float*)(ws + off); off += (size_t)NNZ * 4;

    // CSR build (cnt must start at zero; ws is poisoned each call).
    (void)hipMemsetAsync(cnt, 0, (size_t)N_OUT * 4, stream);
    hist_kernel <<<(NNZ + 255) / 256, 256, 0, stream>>>(row, cnt);
    scan_kernel <<<1, 1024, 0, stream>>>(cnt, offs, cursor);
    place_kernel<<<(NNZ + 255) / 256, 256, 0, stream>>>(row, col, values, cursor, ecol, eval);

    // Pack weight into MFMA B-fragment order (independent of CSR chain).
    packw_kernel<<<KB, 256, 0, stream>>>(weight, packedW);

    // Pool into bf16.
    pool_kernel<<<N_OUT / 4, 256, 0, stream>>>(x, ecol, eval, offs, pooled);

    // Gathered GEMM + bias + ELU.
    dim3 ggrid((N_OUT + 255) / 256, B);
    spiral_mfma<<<ggrid, 256, 0, stream>>>(pooled,
        reinterpret_cast<const bf16x8*>(packedW), sp, bias, out);
}